// Round 8
// baseline (132.940 us; speedup 1.0000x reference)
//
#include <hip/hip_runtime.h>

using f32x4  = __attribute__((ext_vector_type(4))) float;
using f32x16 = __attribute__((ext_vector_type(16))) float;
using bf16x8 = __attribute__((ext_vector_type(8))) short;

__device__ __forceinline__ ushort f2b(float x) {
  union { float f; unsigned u; } v; v.f = x;
  unsigned u = v.u;
  return (ushort)((u + 0x7FFFu + ((u >> 16) & 1u)) >> 16);
}

__device__ __forceinline__ int cvtpk(float lo, float hi) {
  int r;
  asm("v_cvt_pk_bf16_f32 %0, %1, %2" : "=v"(r) : "v"(lo), "v"(hi));
  return r;
}

// ---- all casts in one launch ----
__global__ __launch_bounds__(256) void kcastAll(const float* __restrict__ wqkv,
                                                const float* __restrict__ wout,
                                                const float* __restrict__ x,
                                                ushort* __restrict__ wqkvT,
                                                ushort* __restrict__ woutT,
                                                ushort* __restrict__ xb) {
  int blk = blockIdx.x;
  if (blk < 3072) {
    int i = blk * 256 + threadIdx.x;
    int n = i >> 9, k = i & 511;
    wqkvT[i] = f2b(wqkv[k * 1536 + n]);
  } else if (blk < 4096) {
    int i = (blk - 3072) * 256 + threadIdx.x;
    int n = i >> 9, k = i & 511;
    woutT[i] = f2b(wout[k * 512 + n]);
  } else {
    int t = (blk - 4096) * 256 + threadIdx.x;
    float4 v = ((const float4*)x)[t];
    ushort4 o;
    o.x = f2b(v.x); o.y = f2b(v.y); o.z = f2b(v.z); o.w = f2b(v.w);
    ((ushort4*)xb)[t] = o;
  }
}

// ---- plain 128x128 GEMM, register-staged LDS: C[M][Nc] = A * BT^T + bias ----
__global__ __launch_bounds__(256) void kgemm128(const ushort* __restrict__ A,
                                                const ushort* __restrict__ BT,
                                                const float* __restrict__ bias,
                                                float* __restrict__ C, int Nc) {
  __shared__ __align__(16) ushort As[128 * 64];
  __shared__ __align__(16) ushort Bs[128 * 64];
  const int tid = threadIdx.x;
  const int w = tid >> 6, l = tid & 63;
  const int l15 = l & 15, lq = l >> 4;
  const int wr = w >> 1, wc = w & 1;
  const int bx = blockIdx.x, by = blockIdx.y;
  const ushort* Ag = A + (size_t)bx * 128 * 512;
  const ushort* Bg = BT + (size_t)by * 128 * 512;
  const int srow = l >> 3, scol = (l & 7) * 8;
  f32x4 acc[4][4];
#pragma unroll
  for (int m = 0; m < 4; ++m)
#pragma unroll
    for (int n = 0; n < 4; ++n) acc[m][n] = (f32x4){0.f, 0.f, 0.f, 0.f};
  for (int kt = 0; kt < 8; ++kt) {
    const int c0 = kt * 64 + scol;
    uint4 ra[4], rb[4];
#pragma unroll
    for (int i = 0; i < 4; ++i) {
      const int r = (w * 4 + i) * 8 + srow;
      ra[i] = *(const uint4*)(Ag + (size_t)r * 512 + c0);
      rb[i] = *(const uint4*)(Bg + (size_t)r * 512 + c0);
    }
    __syncthreads();   // previous iteration's LDS reads complete
#pragma unroll
    for (int i = 0; i < 4; ++i) {
      const int r = (w * 4 + i) * 8 + srow;
      *(uint4*)&As[r * 64 + scol] = ra[i];
      *(uint4*)&Bs[r * 64 + scol] = rb[i];
    }
    __syncthreads();   // staged data visible
#pragma unroll
    for (int kk = 0; kk < 2; ++kk) {
      bf16x8 af[4], bfr[4];
#pragma unroll
      for (int m = 0; m < 4; ++m)
        af[m] = *(const bf16x8*)&As[(wr * 64 + m * 16 + l15) * 64 + kk * 32 + lq * 8];
#pragma unroll
      for (int n = 0; n < 4; ++n)
        bfr[n] = *(const bf16x8*)&Bs[(wc * 64 + n * 16 + l15) * 64 + kk * 32 + lq * 8];
#pragma unroll
      for (int m = 0; m < 4; ++m)
#pragma unroll
        for (int n = 0; n < 4; ++n)
          acc[m][n] = __builtin_amdgcn_mfma_f32_16x16x32_bf16(af[m], bfr[n], acc[m][n], 0, 0, 0);
    }
  }
#pragma unroll
  for (int ns = 0; ns < 4; ++ns) {
    const int col = by * 128 + wc * 64 + ns * 16 + l15;
    const float bvv = bias[col];
#pragma unroll
    for (int m = 0; m < 4; ++m) {
      const int row = bx * 128 + wr * 64 + m * 16 + lq * 4;
#pragma unroll
      for (int r = 0; r < 4; ++r)
        C[(size_t)(row + r) * Nc + col] = acc[m][ns][r] + bvv;
    }
  }
}

// ---- forward pose maps (R2-verified): qkv(f32) -> qx + kxF/vxF (MFMA-frag order) ----
__global__ __launch_bounds__(256) void kposef2(const float* __restrict__ qkv,
                                               const float* __restrict__ poses,
                                               ushort* __restrict__ qx,
                                               ushort* __restrict__ kxF,
                                               ushort* __restrict__ vxF) {
  int token = blockIdx.x * 4 + (threadIdx.x >> 6);
  int l = threadIdx.x & 63;
  int b = token >> 11, n = token & 2047;
  const float* P = poses + (size_t)token * 16;
  float R00 = P[0], R01 = P[1], R02 = P[2],  t0 = P[3];
  float R10 = P[4], R11 = P[5], R12 = P[6],  t1 = P[7];
  float R20 = P[8], R21 = P[9], R22 = P[10], t2 = P[11];
  float ti0 = -(R00 * t0 + R10 * t1 + R20 * t2);
  float ti1 = -(R01 * t0 + R11 * t1 + R21 * t2);
  float ti2 = -(R02 * t0 + R12 * t1 + R22 * t2);
  const float* row = qkv + (size_t)token * 1536;
  int tile = n >> 5;
  int kvsel = (n >> 4) & 1;
  int hV = (n >> 3) & 1;
  int jV = n & 7;
  int cK = n & 31;
#pragma unroll
  for (int it = 0; it < 2; it++) {
    int cvi = l + it * 64;          // 4-vec index 0..127
    int hh = cvi >> 4, cc = cvi & 15;
    int bh = b * 8 + hh;
    float4 a;
    a = *(const float4*)(row + cvi * 4);
    ushort4 oq;
    oq.x = f2b(R00 * a.x + R01 * a.y + R02 * a.z);
    oq.y = f2b(R10 * a.x + R11 * a.y + R12 * a.z);
    oq.z = f2b(R20 * a.x + R21 * a.y + R22 * a.z);
    oq.w = f2b(ti0 * a.x + ti1 * a.y + ti2 * a.z + a.w);
    *(ushort4*)(qx + ((size_t)bh * 2048 + n) * 64 + cc * 4) = oq;
    a = *(const float4*)(row + 512 + cvi * 4);
    ushort4 ok;
    ok.x = f2b(R00 * a.x + R01 * a.y + R02 * a.z + t0 * a.w);
    ok.y = f2b(R10 * a.x + R11 * a.y + R12 * a.z + t1 * a.w);
    ok.z = f2b(R20 * a.x + R21 * a.y + R22 * a.z + t2 * a.w);
    ok.w = f2b(a.w);
    int kkd = cc >> 2, hK = (cc >> 1) & 1, jK0 = (cc & 1) * 4;
    size_t kaddr = ((((size_t)bh * 64 + tile) * 4 + kkd) * 2 + hK) * 256 + cK * 8 + jK0;
    *(ushort4*)(kxF + kaddr) = ok;
    a = *(const float4*)(row + 1024 + cvi * 4);
    ushort v0 = f2b(R00 * a.x + R01 * a.y + R02 * a.z + t0 * a.w);
    ushort v1 = f2b(R10 * a.x + R11 * a.y + R12 * a.z + t1 * a.w);
    ushort v2 = f2b(R20 * a.x + R21 * a.y + R22 * a.z + t2 * a.w);
    ushort v3 = f2b(a.w);
    int db = cc >> 3;
    int cV0 = (cc * 4) & 31;
    size_t vaddr = (((((size_t)bh * 64 + tile) * 2 + kvsel) * 2 + db) * 2 + hV) * 256
                 + (size_t)cV0 * 8 + jV;
    vxF[vaddr]      = v0;
    vxF[vaddr + 8]  = v1;
    vxF[vaddr + 16] = v2;
    vxF[vaddr + 24] = v3;
  }
}

// ---- attention (R2-verified kattn2): WG=(bh, 32 q); 4 waves key-split ----
__global__ __launch_bounds__(256) void kattn2(const ushort* __restrict__ qx,
                                              const ushort* __restrict__ kxF,
                                              const ushort* __restrict__ vxF,
                                              const float* __restrict__ poses,
                                              ushort* __restrict__ obuf) {
  __shared__ float Wacc[4][32][68];
  __shared__ float Wm[4][32];
  __shared__ float Wl[4][32];
  const int tid = threadIdx.x;
  const int w = tid >> 6;
  const int l = tid & 63;
  const int c = l & 31;
  const int h = l >> 5;
  const int bid = blockIdx.x;
  const int bh = bid >> 6, qb = bid & 63;

  const ushort* qp = qx + ((size_t)bh * 2048 + qb * 32 + c) * 64 + h * 8;
  bf16x8 qf0 = *(const bf16x8*)(qp);
  bf16x8 qf1 = *(const bf16x8*)(qp + 16);
  bf16x8 qf2 = *(const bf16x8*)(qp + 32);
  bf16x8 qf3 = *(const bf16x8*)(qp + 48);

  f32x16 accO0, accO1;
#pragma unroll
  for (int j = 0; j < 16; j++) { accO0[j] = 0.f; accO1[j] = 0.f; }
  float m = -INFINITY, lsum = 0.f;
  const float cs = 0.125f * 1.44269504089f;

  const ushort* kB = kxF + (size_t)bh * (64 * 2048) + (size_t)w * 2048 + h * 256 + c * 8;
  const ushort* vB = vxF + (size_t)bh * (64 * 2048) + (size_t)w * 2048 + h * 256 + c * 8;
  for (int i = 0; i < 16; i++) {
    const ushort* kt = kB + (size_t)i * 4 * 2048;
    const ushort* vt = vB + (size_t)i * 4 * 2048;
    bf16x8 kf0 = *(const bf16x8*)(kt);
    bf16x8 kf1 = *(const bf16x8*)(kt + 512);
    bf16x8 kf2 = *(const bf16x8*)(kt + 1024);
    bf16x8 kf3 = *(const bf16x8*)(kt + 1536);
    bf16x8 vf00 = *(const bf16x8*)(vt);
    bf16x8 vf01 = *(const bf16x8*)(vt + 512);
    bf16x8 vf10 = *(const bf16x8*)(vt + 1024);
    bf16x8 vf11 = *(const bf16x8*)(vt + 1536);
    f32x16 s;
#pragma unroll
    for (int j = 0; j < 16; j++) s[j] = 0.f;
    s = __builtin_amdgcn_mfma_f32_32x32x16_bf16(kf0, qf0, s, 0, 0, 0);
    s = __builtin_amdgcn_mfma_f32_32x32x16_bf16(kf1, qf1, s, 0, 0, 0);
    s = __builtin_amdgcn_mfma_f32_32x32x16_bf16(kf2, qf2, s, 0, 0, 0);
    s = __builtin_amdgcn_mfma_f32_32x32x16_bf16(kf3, qf3, s, 0, 0, 0);
    float pmax = s[0];
#pragma unroll
    for (int j = 1; j < 16; j++) pmax = fmaxf(pmax, s[j]);
    pmax = fmaxf(pmax, __shfl_xor(pmax, 32, 64));
    float mn = fmaxf(m, pmax * cs);
    float resc = __builtin_amdgcn_exp2f(m - mn);
    m = mn;
    float psum = 0.f;
#pragma unroll
    for (int j = 0; j < 16; j++) {
      float pv = __builtin_amdgcn_exp2f(fmaf(s[j], cs, -mn));
      s[j] = pv;
      psum += pv;
    }
    psum += __shfl_xor(psum, 32, 64);
    lsum = fmaf(lsum, resc, psum);
#pragma unroll
    for (int j = 0; j < 16; j++) { accO0[j] *= resc; accO1[j] *= resc; }
    int pk0 = cvtpk(s[0],  s[1]);
    int pk1 = cvtpk(s[2],  s[3]);
    int pk2 = cvtpk(s[4],  s[5]);
    int pk3 = cvtpk(s[6],  s[7]);
    int pk4 = cvtpk(s[8],  s[9]);
    int pk5 = cvtpk(s[10], s[11]);
    int pk6 = cvtpk(s[12], s[13]);
    int pk7 = cvtpk(s[14], s[15]);
    int X00 = __shfl_xor(h ? pk0 : pk2, 32, 64);
    int X01 = __shfl_xor(h ? pk1 : pk3, 32, 64);
    int X10 = __shfl_xor(h ? pk4 : pk6, 32, 64);
    int X11 = __shfl_xor(h ? pk5 : pk7, 32, 64);
    union { int d[4]; bf16x8 v; } pf0, pf1;
    pf0.d[0] = h ? X00 : pk0;
    pf0.d[1] = h ? X01 : pk1;
    pf0.d[2] = h ? pk2 : X00;
    pf0.d[3] = h ? pk3 : X01;
    pf1.d[0] = h ? X10 : pk4;
    pf1.d[1] = h ? X11 : pk5;
    pf1.d[2] = h ? pk6 : X10;
    pf1.d[3] = h ? pk7 : X11;
    accO0 = __builtin_amdgcn_mfma_f32_32x32x16_bf16(vf00, pf0.v, accO0, 0, 0, 0);
    accO1 = __builtin_amdgcn_mfma_f32_32x32x16_bf16(vf01, pf0.v, accO1, 0, 0, 0);
    accO0 = __builtin_amdgcn_mfma_f32_32x32x16_bf16(vf10, pf1.v, accO0, 0, 0, 0);
    accO1 = __builtin_amdgcn_mfma_f32_32x32x16_bf16(vf11, pf1.v, accO1, 0, 0, 0);
  }
#pragma unroll
  for (int reg = 0; reg < 16; reg++) {
    int d = (reg & 3) + 8 * (reg >> 2) + 4 * h;
    Wacc[w][c][d]      = accO0[reg];
    Wacc[w][c][32 + d] = accO1[reg];
  }
  if (h == 0) { Wm[w][c] = m; Wl[w][c] = lsum; }
  __syncthreads();
  int q = tid >> 3, oct = tid & 7;
  int b = bh >> 3, hh = bh & 7;
  int n = qb * 32 + q;
  float m0 = Wm[0][q], m1 = Wm[1][q], m2 = Wm[2][q], m3 = Wm[3][q];
  float ms = fmaxf(fmaxf(m0, m1), fmaxf(m2, m3));
  float e0 = __builtin_amdgcn_exp2f(m0 - ms);
  float e1 = __builtin_amdgcn_exp2f(m1 - ms);
  float e2 = __builtin_amdgcn_exp2f(m2 - ms);
  float e3 = __builtin_amdgcn_exp2f(m3 - ms);
  float lt = e0 * Wl[0][q] + e1 * Wl[1][q] + e2 * Wl[2][q] + e3 * Wl[3][q];
  float inv = 1.0f / lt;
  float od[8];
#pragma unroll
  for (int j = 0; j < 8; j++) {
    int d = oct * 8 + j;
    od[j] = (e0 * Wacc[0][q][d] + e1 * Wacc[1][q][d] +
             e2 * Wacc[2][q][d] + e3 * Wacc[3][q][d]) * inv;
  }
  const float* P = poses + ((size_t)b * 2048 + n) * 16;
  float R00 = P[0], R01 = P[1], R02 = P[2],  t0 = P[3];
  float R10 = P[4], R11 = P[5], R12 = P[6],  t1 = P[7];
  float R20 = P[8], R21 = P[9], R22 = P[10], t2 = P[11];
  float ti0 = -(R00 * t0 + R10 * t1 + R20 * t2);
  float ti1 = -(R01 * t0 + R11 * t1 + R21 * t2);
  float ti2 = -(R02 * t0 + R12 * t1 + R22 * t2);
  union { ushort u[8]; uint4 v; } ob;
#pragma unroll
  for (int g = 0; g < 2; g++) {
    float a0 = od[4 * g], a1 = od[4 * g + 1], a2 = od[4 * g + 2], a3 = od[4 * g + 3];
    ob.u[4 * g + 0] = f2b(R00 * a0 + R10 * a1 + R20 * a2 + ti0 * a3);
    ob.u[4 * g + 1] = f2b(R01 * a0 + R11 * a1 + R21 * a2 + ti1 * a3);
    ob.u[4 * g + 2] = f2b(R02 * a0 + R12 * a1 + R22 * a2 + ti2 * a3);
    ob.u[4 * g + 3] = f2b(a3);
  }
  *(uint4*)(obuf + ((size_t)b * 2048 + n) * 512 + hh * 64 + oct * 8) = ob.v;
}

extern "C" void kernel_launch(void* const* d_in, const int* in_sizes, int n_in,
                              void* d_out, int out_size, void* d_ws, size_t ws_size,
                              hipStream_t stream) {
  const float* x     = (const float*)d_in[0];
  const float* poses = (const float*)d_in[1];
  const float* w_qkv = (const float*)d_in[2];
  const float* b_qkv = (const float*)d_in[3];
  const float* w_out = (const float*)d_in[4];
  const float* b_out = (const float*)d_in[5];
  float* out = (float*)d_out;
  char* ws = (char*)d_ws;
  const size_t MB = 1024 * 1024;
  ushort* xb    = (ushort*)(ws);            // 4 MB
  ushort* wqkvT = (ushort*)(ws + 4 * MB);   // 1.5 MB
  ushort* woutT = (ushort*)(ws + 6 * MB);   // 0.5 MB
  float*  qkvf  = (float*)(ws + 8 * MB);    // 24 MB [4096][1536]
  ushort* obuf  = (ushort*)(ws + 8 * MB);   // 4 MB, reuses qkvf region (dead after kposef2)
  ushort* qxb   = (ushort*)(ws + 32 * MB);  // 4 MB
  ushort* kxFb  = (ushort*)(ws + 36 * MB);  // 4 MB
  ushort* vxFb  = (ushort*)(ws + 40 * MB);  // 4 MB

  kcastAll<<<6144, 256, 0, stream>>>(w_qkv, w_out, x, wqkvT, woutT, xb);
  dim3 g1(32, 12);
  kgemm128<<<g1, 256, 0, stream>>>(xb, wqkvT, b_qkv, qkvf, 1536);
  kposef2<<<1024, 256, 0, stream>>>(qkvf, poses, qxb, kxFb, vxFb);
  kattn2<<<1024, 256, 0, stream>>>(qxb, kxFb, vxFb, poses, obuf);
  dim3 g2(32, 4);
  kgemm128<<<g2, 256, 0, stream>>>(obuf, woutT, b_out, out, 512);
}

// Round 9
// 129.985 us; speedup vs baseline: 1.0227x; 1.0227x over previous
//
#include <hip/hip_runtime.h>

using f32x4  = __attribute__((ext_vector_type(4))) float;
using f32x16 = __attribute__((ext_vector_type(16))) float;
using bf16x8 = __attribute__((ext_vector_type(8))) short;

__device__ __forceinline__ ushort f2b(float x) {
  union { float f; unsigned u; } v; v.f = x;
  unsigned u = v.u;
  return (ushort)((u + 0x7FFFu + ((u >> 16) & 1u)) >> 16);
}

__device__ __forceinline__ int cvtpk(float lo, float hi) {
  int r;
  asm("v_cvt_pk_bf16_f32 %0, %1, %2" : "=v"(r) : "v"(lo), "v"(hi));
  return r;
}

// ---- all casts in one launch ----
__global__ __launch_bounds__(256) void kcastAll(const float* __restrict__ wqkv,
                                                const float* __restrict__ wout,
                                                const float* __restrict__ x,
                                                ushort* __restrict__ wqkvT,
                                                ushort* __restrict__ woutT,
                                                ushort* __restrict__ xb) {
  int blk = blockIdx.x;
  if (blk < 3072) {
    int i = blk * 256 + threadIdx.x;
    int n = i >> 9, k = i & 511;
    wqkvT[i] = f2b(wqkv[k * 1536 + n]);
  } else if (blk < 4096) {
    int i = (blk - 3072) * 256 + threadIdx.x;
    int n = i >> 9, k = i & 511;
    woutT[i] = f2b(wout[k * 512 + n]);
  } else {
    int t = (blk - 4096) * 256 + threadIdx.x;
    float4 v = ((const float4*)x)[t];
    ushort4 o;
    o.x = f2b(v.x); o.y = f2b(v.y); o.z = f2b(v.z); o.w = f2b(v.w);
    ((ushort4*)xb)[t] = o;
  }
}

// ---- plain 128x128 GEMM, register-staged LDS, PADDED rows (72 elem = 144 B) ----
// Pad kills the 128B-stride bank pathology: writes land on banks {0,4,..,28},
// fragment reads become 2-way (free). See G4 / m136.
__global__ __launch_bounds__(256) void kgemm128(const ushort* __restrict__ A,
                                                const ushort* __restrict__ BT,
                                                const float* __restrict__ bias,
                                                float* __restrict__ C, int Nc) {
  __shared__ __align__(16) ushort As[128 * 72];
  __shared__ __align__(16) ushort Bs[128 * 72];
  const int tid = threadIdx.x;
  const int w = tid >> 6, l = tid & 63;
  const int l15 = l & 15, lq = l >> 4;
  const int wr = w >> 1, wc = w & 1;
  const int bx = blockIdx.x, by = blockIdx.y;
  const ushort* Ag = A + (size_t)bx * 128 * 512;
  const ushort* Bg = BT + (size_t)by * 128 * 512;
  const int srow = l >> 3, scol = (l & 7) * 8;
  f32x4 acc[4][4];
#pragma unroll
  for (int m = 0; m < 4; ++m)
#pragma unroll
    for (int n = 0; n < 4; ++n) acc[m][n] = (f32x4){0.f, 0.f, 0.f, 0.f};
  for (int kt = 0; kt < 8; ++kt) {
    const int c0 = kt * 64 + scol;
    uint4 ra[4], rb[4];
#pragma unroll
    for (int i = 0; i < 4; ++i) {
      const int r = (w * 4 + i) * 8 + srow;
      ra[i] = *(const uint4*)(Ag + (size_t)r * 512 + c0);
      rb[i] = *(const uint4*)(Bg + (size_t)r * 512 + c0);
    }
    __syncthreads();   // previous iteration's LDS reads complete
#pragma unroll
    for (int i = 0; i < 4; ++i) {
      const int r = (w * 4 + i) * 8 + srow;
      *(uint4*)&As[r * 72 + scol] = ra[i];
      *(uint4*)&Bs[r * 72 + scol] = rb[i];
    }
    __syncthreads();   // staged data visible
#pragma unroll
    for (int kk = 0; kk < 2; ++kk) {
      bf16x8 af[4], bfr[4];
#pragma unroll
      for (int m = 0; m < 4; ++m)
        af[m] = *(const bf16x8*)&As[(wr * 64 + m * 16 + l15) * 72 + kk * 32 + lq * 8];
#pragma unroll
      for (int n = 0; n < 4; ++n)
        bfr[n] = *(const bf16x8*)&Bs[(wc * 64 + n * 16 + l15) * 72 + kk * 32 + lq * 8];
#pragma unroll
      for (int m = 0; m < 4; ++m)
#pragma unroll
        for (int n = 0; n < 4; ++n)
          acc[m][n] = __builtin_amdgcn_mfma_f32_16x16x32_bf16(af[m], bfr[n], acc[m][n], 0, 0, 0);
    }
  }
#pragma unroll
  for (int ns = 0; ns < 4; ++ns) {
    const int col = by * 128 + wc * 64 + ns * 16 + l15;
    const float bvv = bias[col];
#pragma unroll
    for (int m = 0; m < 4; ++m) {
      const int row = bx * 128 + wr * 64 + m * 16 + lq * 4;
#pragma unroll
      for (int r = 0; r < 4; ++r)
        C[(size_t)(row + r) * Nc + col] = acc[m][ns][r] + bvv;
    }
  }
}

// ---- forward pose maps (R2-verified): qkv(f32) -> qx + kxF/vxF (MFMA-frag order) ----
__global__ __launch_bounds__(256) void kposef2(const float* __restrict__ qkv,
                                               const float* __restrict__ poses,
                                               ushort* __restrict__ qx,
                                               ushort* __restrict__ kxF,
                                               ushort* __restrict__ vxF) {
  int token = blockIdx.x * 4 + (threadIdx.x >> 6);
  int l = threadIdx.x & 63;
  int b = token >> 11, n = token & 2047;
  const float* P = poses + (size_t)token * 16;
  float R00 = P[0], R01 = P[1], R02 = P[2],  t0 = P[3];
  float R10 = P[4], R11 = P[5], R12 = P[6],  t1 = P[7];
  float R20 = P[8], R21 = P[9], R22 = P[10], t2 = P[11];
  float ti0 = -(R00 * t0 + R10 * t1 + R20 * t2);
  float ti1 = -(R01 * t0 + R11 * t1 + R21 * t2);
  float ti2 = -(R02 * t0 + R12 * t1 + R22 * t2);
  const float* row = qkv + (size_t)token * 1536;
  int tile = n >> 5;
  int kvsel = (n >> 4) & 1;
  int hV = (n >> 3) & 1;
  int jV = n & 7;
  int cK = n & 31;
#pragma unroll
  for (int it = 0; it < 2; it++) {
    int cvi = l + it * 64;          // 4-vec index 0..127
    int hh = cvi >> 4, cc = cvi & 15;
    int bh = b * 8 + hh;
    float4 a;
    a = *(const float4*)(row + cvi * 4);
    ushort4 oq;
    oq.x = f2b(R00 * a.x + R01 * a.y + R02 * a.z);
    oq.y = f2b(R10 * a.x + R11 * a.y + R12 * a.z);
    oq.z = f2b(R20 * a.x + R21 * a.y + R22 * a.z);
    oq.w = f2b(ti0 * a.x + ti1 * a.y + ti2 * a.z + a.w);
    *(ushort4*)(qx + ((size_t)bh * 2048 + n) * 64 + cc * 4) = oq;
    a = *(const float4*)(row + 512 + cvi * 4);
    ushort4 ok;
    ok.x = f2b(R00 * a.x + R01 * a.y + R02 * a.z + t0 * a.w);
    ok.y = f2b(R10 * a.x + R11 * a.y + R12 * a.z + t1 * a.w);
    ok.z = f2b(R20 * a.x + R21 * a.y + R22 * a.z + t2 * a.w);
    ok.w = f2b(a.w);
    int kkd = cc >> 2, hK = (cc >> 1) & 1, jK0 = (cc & 1) * 4;
    size_t kaddr = ((((size_t)bh * 64 + tile) * 4 + kkd) * 2 + hK) * 256 + cK * 8 + jK0;
    *(ushort4*)(kxF + kaddr) = ok;
    a = *(const float4*)(row + 1024 + cvi * 4);
    ushort v0 = f2b(R00 * a.x + R01 * a.y + R02 * a.z + t0 * a.w);
    ushort v1 = f2b(R10 * a.x + R11 * a.y + R12 * a.z + t1 * a.w);
    ushort v2 = f2b(R20 * a.x + R21 * a.y + R22 * a.z + t2 * a.w);
    ushort v3 = f2b(a.w);
    int db = cc >> 3;
    int cV0 = (cc * 4) & 31;
    size_t vaddr = (((((size_t)bh * 64 + tile) * 2 + kvsel) * 2 + db) * 2 + hV) * 256
                 + (size_t)cV0 * 8 + jV;
    vxF[vaddr]      = v0;
    vxF[vaddr + 8]  = v1;
    vxF[vaddr + 16] = v2;
    vxF[vaddr + 24] = v3;
  }
}

// ---- attention (R2-verified kattn2): WG=(bh, 32 q); 4 waves key-split ----
__global__ __launch_bounds__(256) void kattn2(const ushort* __restrict__ qx,
                                              const ushort* __restrict__ kxF,
                                              const ushort* __restrict__ vxF,
                                              const float* __restrict__ poses,
                                              ushort* __restrict__ obuf) {
  __shared__ float Wacc[4][32][68];
  __shared__ float Wm[4][32];
  __shared__ float Wl[4][32];
  const int tid = threadIdx.x;
  const int w = tid >> 6;
  const int l = tid & 63;
  const int c = l & 31;
  const int h = l >> 5;
  const int bid = blockIdx.x;
  const int bh = bid >> 6, qb = bid & 63;

  const ushort* qp = qx + ((size_t)bh * 2048 + qb * 32 + c) * 64 + h * 8;
  bf16x8 qf0 = *(const bf16x8*)(qp);
  bf16x8 qf1 = *(const bf16x8*)(qp + 16);
  bf16x8 qf2 = *(const bf16x8*)(qp + 32);
  bf16x8 qf3 = *(const bf16x8*)(qp + 48);

  f32x16 accO0, accO1;
#pragma unroll
  for (int j = 0; j < 16; j++) { accO0[j] = 0.f; accO1[j] = 0.f; }
  float m = -INFINITY, lsum = 0.f;
  const float cs = 0.125f * 1.44269504089f;

  const ushort* kB = kxF + (size_t)bh * (64 * 2048) + (size_t)w * 2048 + h * 256 + c * 8;
  const ushort* vB = vxF + (size_t)bh * (64 * 2048) + (size_t)w * 2048 + h * 256 + c * 8;
  for (int i = 0; i < 16; i++) {
    const ushort* kt = kB + (size_t)i * 4 * 2048;
    const ushort* vt = vB + (size_t)i * 4 * 2048;
    bf16x8 kf0 = *(const bf16x8*)(kt);
    bf16x8 kf1 = *(const bf16x8*)(kt + 512);
    bf16x8 kf2 = *(const bf16x8*)(kt + 1024);
    bf16x8 kf3 = *(const bf16x8*)(kt + 1536);
    bf16x8 vf00 = *(const bf16x8*)(vt);
    bf16x8 vf01 = *(const bf16x8*)(vt + 512);
    bf16x8 vf10 = *(const bf16x8*)(vt + 1024);
    bf16x8 vf11 = *(const bf16x8*)(vt + 1536);
    f32x16 s;
#pragma unroll
    for (int j = 0; j < 16; j++) s[j] = 0.f;
    s = __builtin_amdgcn_mfma_f32_32x32x16_bf16(kf0, qf0, s, 0, 0, 0);
    s = __builtin_amdgcn_mfma_f32_32x32x16_bf16(kf1, qf1, s, 0, 0, 0);
    s = __builtin_amdgcn_mfma_f32_32x32x16_bf16(kf2, qf2, s, 0, 0, 0);
    s = __builtin_amdgcn_mfma_f32_32x32x16_bf16(kf3, qf3, s, 0, 0, 0);
    float pmax = s[0];
#pragma unroll
    for (int j = 1; j < 16; j++) pmax = fmaxf(pmax, s[j]);
    pmax = fmaxf(pmax, __shfl_xor(pmax, 32, 64));
    float mn = fmaxf(m, pmax * cs);
    float resc = __builtin_amdgcn_exp2f(m - mn);
    m = mn;
    float psum = 0.f;
#pragma unroll
    for (int j = 0; j < 16; j++) {
      float pv = __builtin_amdgcn_exp2f(fmaf(s[j], cs, -mn));
      s[j] = pv;
      psum += pv;
    }
    psum += __shfl_xor(psum, 32, 64);
    lsum = fmaf(lsum, resc, psum);
#pragma unroll
    for (int j = 0; j < 16; j++) { accO0[j] *= resc; accO1[j] *= resc; }
    int pk0 = cvtpk(s[0],  s[1]);
    int pk1 = cvtpk(s[2],  s[3]);
    int pk2 = cvtpk(s[4],  s[5]);
    int pk3 = cvtpk(s[6],  s[7]);
    int pk4 = cvtpk(s[8],  s[9]);
    int pk5 = cvtpk(s[10], s[11]);
    int pk6 = cvtpk(s[12], s[13]);
    int pk7 = cvtpk(s[14], s[15]);
    int X00 = __shfl_xor(h ? pk0 : pk2, 32, 64);
    int X01 = __shfl_xor(h ? pk1 : pk3, 32, 64);
    int X10 = __shfl_xor(h ? pk4 : pk6, 32, 64);
    int X11 = __shfl_xor(h ? pk5 : pk7, 32, 64);
    union { int d[4]; bf16x8 v; } pf0, pf1;
    pf0.d[0] = h ? X00 : pk0;
    pf0.d[1] = h ? X01 : pk1;
    pf0.d[2] = h ? pk2 : X00;
    pf0.d[3] = h ? pk3 : X01;
    pf1.d[0] = h ? X10 : pk4;
    pf1.d[1] = h ? X11 : pk5;
    pf1.d[2] = h ? pk6 : X10;
    pf1.d[3] = h ? pk7 : X11;
    accO0 = __builtin_amdgcn_mfma_f32_32x32x16_bf16(vf00, pf0.v, accO0, 0, 0, 0);
    accO1 = __builtin_amdgcn_mfma_f32_32x32x16_bf16(vf01, pf0.v, accO1, 0, 0, 0);
    accO0 = __builtin_amdgcn_mfma_f32_32x32x16_bf16(vf10, pf1.v, accO0, 0, 0, 0);
    accO1 = __builtin_amdgcn_mfma_f32_32x32x16_bf16(vf11, pf1.v, accO1, 0, 0, 0);
  }
#pragma unroll
  for (int reg = 0; reg < 16; reg++) {
    int d = (reg & 3) + 8 * (reg >> 2) + 4 * h;
    Wacc[w][c][d]      = accO0[reg];
    Wacc[w][c][32 + d] = accO1[reg];
  }
  if (h == 0) { Wm[w][c] = m; Wl[w][c] = lsum; }
  __syncthreads();
  int q = tid >> 3, oct = tid & 7;
  int b = bh >> 3, hh = bh & 7;
  int n = qb * 32 + q;
  float m0 = Wm[0][q], m1 = Wm[1][q], m2 = Wm[2][q], m3 = Wm[3][q];
  float ms = fmaxf(fmaxf(m0, m1), fmaxf(m2, m3));
  float e0 = __builtin_amdgcn_exp2f(m0 - ms);
  float e1 = __builtin_amdgcn_exp2f(m1 - ms);
  float e2 = __builtin_amdgcn_exp2f(m2 - ms);
  float e3 = __builtin_amdgcn_exp2f(m3 - ms);
  float lt = e0 * Wl[0][q] + e1 * Wl[1][q] + e2 * Wl[2][q] + e3 * Wl[3][q];
  float inv = 1.0f / lt;
  float od[8];
#pragma unroll
  for (int j = 0; j < 8; j++) {
    int d = oct * 8 + j;
    od[j] = (e0 * Wacc[0][q][d] + e1 * Wacc[1][q][d] +
             e2 * Wacc[2][q][d] + e3 * Wacc[3][q][d]) * inv;
  }
  const float* P = poses + ((size_t)b * 2048 + n) * 16;
  float R00 = P[0], R01 = P[1], R02 = P[2],  t0 = P[3];
  float R10 = P[4], R11 = P[5], R12 = P[6],  t1 = P[7];
  float R20 = P[8], R21 = P[9], R22 = P[10], t2 = P[11];
  float ti0 = -(R00 * t0 + R10 * t1 + R20 * t2);
  float ti1 = -(R01 * t0 + R11 * t1 + R21 * t2);
  float ti2 = -(R02 * t0 + R12 * t1 + R22 * t2);
  union { ushort u[8]; uint4 v; } ob;
#pragma unroll
  for (int g = 0; g < 2; g++) {
    float a0 = od[4 * g], a1 = od[4 * g + 1], a2 = od[4 * g + 2], a3 = od[4 * g + 3];
    ob.u[4 * g + 0] = f2b(R00 * a0 + R10 * a1 + R20 * a2 + ti0 * a3);
    ob.u[4 * g + 1] = f2b(R01 * a0 + R11 * a1 + R21 * a2 + ti1 * a3);
    ob.u[4 * g + 2] = f2b(R02 * a0 + R12 * a1 + R22 * a2 + ti2 * a3);
    ob.u[4 * g + 3] = f2b(a3);
  }
  *(uint4*)(obuf + ((size_t)b * 2048 + n) * 512 + hh * 64 + oct * 8) = ob.v;
}

extern "C" void kernel_launch(void* const* d_in, const int* in_sizes, int n_in,
                              void* d_out, int out_size, void* d_ws, size_t ws_size,
                              hipStream_t stream) {
  const float* x     = (const float*)d_in[0];
  const float* poses = (const float*)d_in[1];
  const float* w_qkv = (const float*)d_in[2];
  const float* b_qkv = (const float*)d_in[3];
  const float* w_out = (const float*)d_in[4];
  const float* b_out = (const float*)d_in[5];
  float* out = (float*)d_out;
  char* ws = (char*)d_ws;
  const size_t MB = 1024 * 1024;
  ushort* xb    = (ushort*)(ws);            // 4 MB
  ushort* wqkvT = (ushort*)(ws + 4 * MB);   // 1.5 MB
  ushort* woutT = (ushort*)(ws + 6 * MB);   // 0.5 MB
  float*  qkvf  = (float*)(ws + 8 * MB);    // 24 MB [4096][1536]
  ushort* obuf  = (ushort*)(ws + 8 * MB);   // 4 MB, reuses qkvf region (dead after kposef2)
  ushort* qxb   = (ushort*)(ws + 32 * MB);  // 4 MB
  ushort* kxFb  = (ushort*)(ws + 36 * MB);  // 4 MB
  ushort* vxFb  = (ushort*)(ws + 40 * MB);  // 4 MB

  kcastAll<<<6144, 256, 0, stream>>>(w_qkv, w_out, x, wqkvT, woutT, xb);
  dim3 g1(32, 12);
  kgemm128<<<g1, 256, 0, stream>>>(xb, wqkvT, b_qkv, qkvf, 1536);
  kposef2<<<1024, 256, 0, stream>>>(qkvf, poses, qxb, kxFb, vxFb);
  kattn2<<<1024, 256, 0, stream>>>(qxb, kxFb, vxFb, poses, obuf);
  dim3 g2(32, 4);
  kgemm128<<<g2, 256, 0, stream>>>(obuf, woutT, b_out, out, 512);
}

// Round 10
// 93.912 us; speedup vs baseline: 1.4156x; 1.3841x over previous
//
#include <hip/hip_runtime.h>

using f32x4  = __attribute__((ext_vector_type(4))) float;
using f32x16 = __attribute__((ext_vector_type(16))) float;
using bf16x8 = __attribute__((ext_vector_type(8))) short;

__device__ __forceinline__ ushort f2b(float x) {
  union { float f; unsigned u; } v; v.f = x;
  unsigned u = v.u;
  return (ushort)((u + 0x7FFFu + ((u >> 16) & 1u)) >> 16);
}

__device__ __forceinline__ int cvtpk(float lo, float hi) {
  int r;
  asm("v_cvt_pk_bf16_f32 %0, %1, %2" : "=v"(r) : "v"(lo), "v"(hi));
  return r;
}

__device__ __forceinline__ void gload16(const ushort* g, ushort* l) {
  __builtin_amdgcn_global_load_lds(
      (const __attribute__((address_space(1))) unsigned int*)g,
      (__attribute__((address_space(3))) unsigned int*)l, 16, 0, 0);
}

// ---- all casts in one launch ----
__global__ __launch_bounds__(256) void kcastAll(const float* __restrict__ wqkv,
                                                const float* __restrict__ wout,
                                                const float* __restrict__ x,
                                                ushort* __restrict__ wqkvT,
                                                ushort* __restrict__ woutT,
                                                ushort* __restrict__ xb) {
  int blk = blockIdx.x;
  if (blk < 3072) {
    int i = blk * 256 + threadIdx.x;
    int n = i >> 9, k = i & 511;
    wqkvT[i] = f2b(wqkv[k * 1536 + n]);
  } else if (blk < 4096) {
    int i = (blk - 3072) * 256 + threadIdx.x;
    int n = i >> 9, k = i & 511;
    woutT[i] = f2b(wout[k * 512 + n]);
  } else {
    int t = (blk - 4096) * 256 + threadIdx.x;
    float4 v = ((const float4*)x)[t];
    ushort4 o;
    o.x = f2b(v.x); o.y = f2b(v.y); o.z = f2b(v.z); o.w = f2b(v.w);
    ((ushort4*)xb)[t] = o;
  }
}

// ---- plain 128x128 GEMM, global_load_lds staging (R3-proven inner loop) ----
// Linear [128][64] LDS (DMA dest must be wave-uniform base + lane*16).
__global__ __launch_bounds__(256) void kgemm128(const ushort* __restrict__ A,
                                                const ushort* __restrict__ BT,
                                                const float* __restrict__ bias,
                                                float* __restrict__ C, int Nc) {
  __shared__ __align__(16) ushort As[128 * 64];
  __shared__ __align__(16) ushort Bs[128 * 64];
  const int tid = threadIdx.x;
  const int w = tid >> 6, l = tid & 63;
  const int l15 = l & 15, lq = l >> 4;
  const int wr = w >> 1, wc = w & 1;
  const int bx = blockIdx.x, by = blockIdx.y;
  const ushort* Ag = A + (size_t)bx * 128 * 512;
  const ushort* Bg = BT + (size_t)by * 128 * 512;
  const int srow = l >> 3, scol = (l & 7) * 8;
  f32x4 acc[4][4];
#pragma unroll
  for (int m = 0; m < 4; ++m)
#pragma unroll
    for (int n = 0; n < 4; ++n) acc[m][n] = (f32x4){0.f, 0.f, 0.f, 0.f};
  for (int kt = 0; kt < 8; ++kt) {
    __syncthreads();   // previous iteration's LDS reads complete
    const int c0 = kt * 64 + scol;
#pragma unroll
    for (int i = 0; i < 4; ++i) {
      const int r = (w * 4 + i) * 8 + srow;
      gload16(Ag + (size_t)r * 512 + c0, &As[(w * 4 + i) * 512]);
      gload16(Bg + (size_t)r * 512 + c0, &Bs[(w * 4 + i) * 512]);
    }
    __syncthreads();   // vmcnt drain + visibility
#pragma unroll
    for (int kk = 0; kk < 2; ++kk) {
      bf16x8 af[4], bfr[4];
#pragma unroll
      for (int m = 0; m < 4; ++m)
        af[m] = *(const bf16x8*)&As[(wr * 64 + m * 16 + l15) * 64 + kk * 32 + lq * 8];
#pragma unroll
      for (int n = 0; n < 4; ++n)
        bfr[n] = *(const bf16x8*)&Bs[(wc * 64 + n * 16 + l15) * 64 + kk * 32 + lq * 8];
#pragma unroll
      for (int m = 0; m < 4; ++m)
#pragma unroll
        for (int n = 0; n < 4; ++n)
          acc[m][n] = __builtin_amdgcn_mfma_f32_16x16x32_bf16(af[m], bfr[n], acc[m][n], 0, 0, 0);
    }
  }
#pragma unroll
  for (int ns = 0; ns < 4; ++ns) {
    const int col = by * 128 + wc * 64 + ns * 16 + l15;
    const float bvv = bias[col];
#pragma unroll
    for (int m = 0; m < 4; ++m) {
      const int row = bx * 128 + wr * 64 + m * 16 + lq * 4;
#pragma unroll
      for (int r = 0; r < 4; ++r)
        C[(size_t)(row + r) * Nc + col] = acc[m][ns][r] + bvv;
    }
  }
}

// ---- forward pose maps (R2-verified): qkv(f32) -> qx + kxF/vxF (MFMA-frag order) ----
__global__ __launch_bounds__(256) void kposef2(const float* __restrict__ qkv,
                                               const float* __restrict__ poses,
                                               ushort* __restrict__ qx,
                                               ushort* __restrict__ kxF,
                                               ushort* __restrict__ vxF) {
  int token = blockIdx.x * 4 + (threadIdx.x >> 6);
  int l = threadIdx.x & 63;
  int b = token >> 11, n = token & 2047;
  const float* P = poses + (size_t)token * 16;
  float R00 = P[0], R01 = P[1], R02 = P[2],  t0 = P[3];
  float R10 = P[4], R11 = P[5], R12 = P[6],  t1 = P[7];
  float R20 = P[8], R21 = P[9], R22 = P[10], t2 = P[11];
  float ti0 = -(R00 * t0 + R10 * t1 + R20 * t2);
  float ti1 = -(R01 * t0 + R11 * t1 + R21 * t2);
  float ti2 = -(R02 * t0 + R12 * t1 + R22 * t2);
  const float* row = qkv + (size_t)token * 1536;
  int tile = n >> 5;
  int kvsel = (n >> 4) & 1;
  int hV = (n >> 3) & 1;
  int jV = n & 7;
  int cK = n & 31;
#pragma unroll
  for (int it = 0; it < 2; it++) {
    int cvi = l + it * 64;          // 4-vec index 0..127
    int hh = cvi >> 4, cc = cvi & 15;
    int bh = b * 8 + hh;
    float4 a;
    a = *(const float4*)(row + cvi * 4);
    ushort4 oq;
    oq.x = f2b(R00 * a.x + R01 * a.y + R02 * a.z);
    oq.y = f2b(R10 * a.x + R11 * a.y + R12 * a.z);
    oq.z = f2b(R20 * a.x + R21 * a.y + R22 * a.z);
    oq.w = f2b(ti0 * a.x + ti1 * a.y + ti2 * a.z + a.w);
    *(ushort4*)(qx + ((size_t)bh * 2048 + n) * 64 + cc * 4) = oq;
    a = *(const float4*)(row + 512 + cvi * 4);
    ushort4 ok;
    ok.x = f2b(R00 * a.x + R01 * a.y + R02 * a.z + t0 * a.w);
    ok.y = f2b(R10 * a.x + R11 * a.y + R12 * a.z + t1 * a.w);
    ok.z = f2b(R20 * a.x + R21 * a.y + R22 * a.z + t2 * a.w);
    ok.w = f2b(a.w);
    int kkd = cc >> 2, hK = (cc >> 1) & 1, jK0 = (cc & 1) * 4;
    size_t kaddr = ((((size_t)bh * 64 + tile) * 4 + kkd) * 2 + hK) * 256 + cK * 8 + jK0;
    *(ushort4*)(kxF + kaddr) = ok;
    a = *(const float4*)(row + 1024 + cvi * 4);
    ushort v0 = f2b(R00 * a.x + R01 * a.y + R02 * a.z + t0 * a.w);
    ushort v1 = f2b(R10 * a.x + R11 * a.y + R12 * a.z + t1 * a.w);
    ushort v2 = f2b(R20 * a.x + R21 * a.y + R22 * a.z + t2 * a.w);
    ushort v3 = f2b(a.w);
    int db = cc >> 3;
    int cV0 = (cc * 4) & 31;
    size_t vaddr = (((((size_t)bh * 64 + tile) * 2 + kvsel) * 2 + db) * 2 + hV) * 256
                 + (size_t)cV0 * 8 + jV;
    vxF[vaddr]      = v0;
    vxF[vaddr + 8]  = v1;
    vxF[vaddr + 16] = v2;
    vxF[vaddr + 24] = v3;
  }
}

// ---- attention (R2-verified kattn2): WG=(bh, 32 q); 4 waves key-split ----
__global__ __launch_bounds__(256) void kattn2(const ushort* __restrict__ qx,
                                              const ushort* __restrict__ kxF,
                                              const ushort* __restrict__ vxF,
                                              const float* __restrict__ poses,
                                              ushort* __restrict__ obuf) {
  __shared__ float Wacc[4][32][68];
  __shared__ float Wm[4][32];
  __shared__ float Wl[4][32];
  const int tid = threadIdx.x;
  const int w = tid >> 6;
  const int l = tid & 63;
  const int c = l & 31;
  const int h = l >> 5;
  const int bid = blockIdx.x;
  const int bh = bid >> 6, qb = bid & 63;

  const ushort* qp = qx + ((size_t)bh * 2048 + qb * 32 + c) * 64 + h * 8;
  bf16x8 qf0 = *(const bf16x8*)(qp);
  bf16x8 qf1 = *(const bf16x8*)(qp + 16);
  bf16x8 qf2 = *(const bf16x8*)(qp + 32);
  bf16x8 qf3 = *(const bf16x8*)(qp + 48);

  f32x16 accO0, accO1;
#pragma unroll
  for (int j = 0; j < 16; j++) { accO0[j] = 0.f; accO1[j] = 0.f; }
  float m = -INFINITY, lsum = 0.f;
  const float cs = 0.125f * 1.44269504089f;

  const ushort* kB = kxF + (size_t)bh * (64 * 2048) + (size_t)w * 2048 + h * 256 + c * 8;
  const ushort* vB = vxF + (size_t)bh * (64 * 2048) + (size_t)w * 2048 + h * 256 + c * 8;
  for (int i = 0; i < 16; i++) {
    const ushort* kt = kB + (size_t)i * 4 * 2048;
    const ushort* vt = vB + (size_t)i * 4 * 2048;
    bf16x8 kf0 = *(const bf16x8*)(kt);
    bf16x8 kf1 = *(const bf16x8*)(kt + 512);
    bf16x8 kf2 = *(const bf16x8*)(kt + 1024);
    bf16x8 kf3 = *(const bf16x8*)(kt + 1536);
    bf16x8 vf00 = *(const bf16x8*)(vt);
    bf16x8 vf01 = *(const bf16x8*)(vt + 512);
    bf16x8 vf10 = *(const bf16x8*)(vt + 1024);
    bf16x8 vf11 = *(const bf16x8*)(vt + 1536);
    f32x16 s;
#pragma unroll
    for (int j = 0; j < 16; j++) s[j] = 0.f;
    s = __builtin_amdgcn_mfma_f32_32x32x16_bf16(kf0, qf0, s, 0, 0, 0);
    s = __builtin_amdgcn_mfma_f32_32x32x16_bf16(kf1, qf1, s, 0, 0, 0);
    s = __builtin_amdgcn_mfma_f32_32x32x16_bf16(kf2, qf2, s, 0, 0, 0);
    s = __builtin_amdgcn_mfma_f32_32x32x16_bf16(kf3, qf3, s, 0, 0, 0);
    float pmax = s[0];
#pragma unroll
    for (int j = 1; j < 16; j++) pmax = fmaxf(pmax, s[j]);
    pmax = fmaxf(pmax, __shfl_xor(pmax, 32, 64));
    float mn = fmaxf(m, pmax * cs);
    float resc = __builtin_amdgcn_exp2f(m - mn);
    m = mn;
    float psum = 0.f;
#pragma unroll
    for (int j = 0; j < 16; j++) {
      float pv = __builtin_amdgcn_exp2f(fmaf(s[j], cs, -mn));
      s[j] = pv;
      psum += pv;
    }
    psum += __shfl_xor(psum, 32, 64);
    lsum = fmaf(lsum, resc, psum);
#pragma unroll
    for (int j = 0; j < 16; j++) { accO0[j] *= resc; accO1[j] *= resc; }
    int pk0 = cvtpk(s[0],  s[1]);
    int pk1 = cvtpk(s[2],  s[3]);
    int pk2 = cvtpk(s[4],  s[5]);
    int pk3 = cvtpk(s[6],  s[7]);
    int pk4 = cvtpk(s[8],  s[9]);
    int pk5 = cvtpk(s[10], s[11]);
    int pk6 = cvtpk(s[12], s[13]);
    int pk7 = cvtpk(s[14], s[15]);
    int X00 = __shfl_xor(h ? pk0 : pk2, 32, 64);
    int X01 = __shfl_xor(h ? pk1 : pk3, 32, 64);
    int X10 = __shfl_xor(h ? pk4 : pk6, 32, 64);
    int X11 = __shfl_xor(h ? pk5 : pk7, 32, 64);
    union { int d[4]; bf16x8 v; } pf0, pf1;
    pf0.d[0] = h ? X00 : pk0;
    pf0.d[1] = h ? X01 : pk1;
    pf0.d[2] = h ? pk2 : X00;
    pf0.d[3] = h ? pk3 : X01;
    pf1.d[0] = h ? X10 : pk4;
    pf1.d[1] = h ? X11 : pk5;
    pf1.d[2] = h ? pk6 : X10;
    pf1.d[3] = h ? pk7 : X11;
    accO0 = __builtin_amdgcn_mfma_f32_32x32x16_bf16(vf00, pf0.v, accO0, 0, 0, 0);
    accO1 = __builtin_amdgcn_mfma_f32_32x32x16_bf16(vf01, pf0.v, accO1, 0, 0, 0);
    accO0 = __builtin_amdgcn_mfma_f32_32x32x16_bf16(vf10, pf1.v, accO0, 0, 0, 0);
    accO1 = __builtin_amdgcn_mfma_f32_32x32x16_bf16(vf11, pf1.v, accO1, 0, 0, 0);
  }
#pragma unroll
  for (int reg = 0; reg < 16; reg++) {
    int d = (reg & 3) + 8 * (reg >> 2) + 4 * h;
    Wacc[w][c][d]      = accO0[reg];
    Wacc[w][c][32 + d] = accO1[reg];
  }
  if (h == 0) { Wm[w][c] = m; Wl[w][c] = lsum; }
  __syncthreads();
  int q = tid >> 3, oct = tid & 7;
  int b = bh >> 3, hh = bh & 7;
  int n = qb * 32 + q;
  float m0 = Wm[0][q], m1 = Wm[1][q], m2 = Wm[2][q], m3 = Wm[3][q];
  float ms = fmaxf(fmaxf(m0, m1), fmaxf(m2, m3));
  float e0 = __builtin_amdgcn_exp2f(m0 - ms);
  float e1 = __builtin_amdgcn_exp2f(m1 - ms);
  float e2 = __builtin_amdgcn_exp2f(m2 - ms);
  float e3 = __builtin_amdgcn_exp2f(m3 - ms);
  float lt = e0 * Wl[0][q] + e1 * Wl[1][q] + e2 * Wl[2][q] + e3 * Wl[3][q];
  float inv = 1.0f / lt;
  float od[8];
#pragma unroll
  for (int j = 0; j < 8; j++) {
    int d = oct * 8 + j;
    od[j] = (e0 * Wacc[0][q][d] + e1 * Wacc[1][q][d] +
             e2 * Wacc[2][q][d] + e3 * Wacc[3][q][d]) * inv;
  }
  const float* P = poses + ((size_t)b * 2048 + n) * 16;
  float R00 = P[0], R01 = P[1], R02 = P[2],  t0 = P[3];
  float R10 = P[4], R11 = P[5], R12 = P[6],  t1 = P[7];
  float R20 = P[8], R21 = P[9], R22 = P[10], t2 = P[11];
  float ti0 = -(R00 * t0 + R10 * t1 + R20 * t2);
  float ti1 = -(R01 * t0 + R11 * t1 + R21 * t2);
  float ti2 = -(R02 * t0 + R12 * t1 + R22 * t2);
  union { ushort u[8]; uint4 v; } ob;
#pragma unroll
  for (int g = 0; g < 2; g++) {
    float a0 = od[4 * g], a1 = od[4 * g + 1], a2 = od[4 * g + 2], a3 = od[4 * g + 3];
    ob.u[4 * g + 0] = f2b(R00 * a0 + R10 * a1 + R20 * a2 + ti0 * a3);
    ob.u[4 * g + 1] = f2b(R01 * a0 + R11 * a1 + R21 * a2 + ti1 * a3);
    ob.u[4 * g + 2] = f2b(R02 * a0 + R12 * a1 + R22 * a2 + ti2 * a3);
    ob.u[4 * g + 3] = f2b(a3);
  }
  *(uint4*)(obuf + ((size_t)b * 2048 + n) * 512 + hh * 64 + oct * 8) = ob.v;
}

extern "C" void kernel_launch(void* const* d_in, const int* in_sizes, int n_in,
                              void* d_out, int out_size, void* d_ws, size_t ws_size,
                              hipStream_t stream) {
  const float* x     = (const float*)d_in[0];
  const float* poses = (const float*)d_in[1];
  const float* w_qkv = (const float*)d_in[2];
  const float* b_qkv = (const float*)d_in[3];
  const float* w_out = (const float*)d_in[4];
  const float* b_out = (const float*)d_in[5];
  float* out = (float*)d_out;
  char* ws = (char*)d_ws;
  const size_t MB = 1024 * 1024;
  ushort* xb    = (ushort*)(ws);            // 4 MB
  ushort* wqkvT = (ushort*)(ws + 4 * MB);   // 1.5 MB
  ushort* woutT = (ushort*)(ws + 6 * MB);   // 0.5 MB
  float*  qkvf  = (float*)(ws + 8 * MB);    // 24 MB [4096][1536]
  ushort* obuf  = (ushort*)(ws + 8 * MB);   // 4 MB, reuses qkvf region (dead after kposef2)
  ushort* qxb   = (ushort*)(ws + 32 * MB);  // 4 MB
  ushort* kxFb  = (ushort*)(ws + 36 * MB);  // 4 MB
  ushort* vxFb  = (ushort*)(ws + 40 * MB);  // 4 MB

  kcastAll<<<6144, 256, 0, stream>>>(w_qkv, w_out, x, wqkvT, woutT, xb);
  dim3 g1(32, 12);
  kgemm128<<<g1, 256, 0, stream>>>(xb, wqkvT, b_qkv, qkvf, 1536);
  kposef2<<<1024, 256, 0, stream>>>(qkvf, poses, qxb, kxFb, vxFb);
  kattn2<<<1024, 256, 0, stream>>>(qxb, kxFb, vxFb, poses, obuf);
  dim3 g2(32, 4);
  kgemm128<<<g2, 256, 0, stream>>>(obuf, woutT, b_out, out, 512);
}